// Round 1
// 357.918 us; speedup vs baseline: 1.0335x; 1.0335x over previous
//
#include <hip/hip_runtime.h>
#include <math.h>

// GaussianConditionalStanh: symbols = searchsorted(mid, x - mean, side='left')
// (nearest codebook level), dequant = codebook[symbols] + mean.
//
// R1: linear 59-compare scan -> compute-serialized, 137 us.
// R2: uniform-grid guess + exact sentinel-walk fixup in LDS -> ~96 us kernel.
// R3 (this): the grid-stride loop kept only 2 loads in flight per lane and the
// LDS walk chained across iterations (unknown trip count blocks pipelining).
// n4 = 7,077,888 = 6912 blocks x 1024 float4 EXACTLY, so switch to an
// exact-cover launch: each thread issues 8 back-to-back dwordx4 loads
// (4 x-tiles + 4 mean-tiles, 128 B in flight), then runs all 16 searchsorted
// walks interleaved (ILP across LDS latency chains), then streams the stores
// out with nontemporal hints (zero reuse -> don't thrash L2).

namespace {

constexpr int kL = 60;  // codebook size
typedef float f4 __attribute__((ext_vector_type(4)));

__device__ __forceinline__ int find_idx(float y, const float* __restrict__ ms,
                                        float c0, float invd) {
    // initial guess in level space (any value works; fixup makes it exact)
    float t = (y - c0) * invd + 0.5f;
    int g = (int)t;                       // trunc; clamp below
    g = max(0, min(g, kL - 1));
    // ms[0] = -inf, ms[1..59] = mid[0..58], ms[60..63] = +inf
    while (y > ms[g + 1]) ++g;            // ascend; inf sentinel stops at 59
    while (y <= ms[g]) --g;               // descend; -inf sentinel stops at 0
    return g;                             // == count(mid < y)  (searchsorted 'left')
}

__global__ __launch_bounds__(256) void stanh_quant_kernel(
    const float* __restrict__ x,
    const float* __restrict__ mean,
    const float* __restrict__ cb,
    float* __restrict__ sym_out,
    float* __restrict__ deq_out,
    int n4)
{
    __shared__ float cb_s[kL];
    __shared__ float ms[kL + 4];   // sentinel-padded midpoints

    const int tid = threadIdx.x;
    if (tid < kL) cb_s[tid] = cb[tid];
    if (tid == 0) ms[0] = -INFINITY;
    if (tid < kL - 1) ms[tid + 1] = 0.5f * (cb[tid] + cb[tid + 1]);  // exact ref arith
    if (tid >= kL - 1 && tid < kL + 3) ms[tid + 1] = INFINITY;       // ms[60..63]
    __syncthreads();

    // uniform-grid model (wave-uniform scalar math, s_load'ed)
    const float c0 = cb[0];
    const float invd = 59.0f / (cb[kL - 1] - c0);

    const f4* __restrict__ x4 = (const f4*)x;
    const f4* __restrict__ m4 = (const f4*)mean;
    f4* __restrict__ s4 = (f4*)sym_out;
    f4* __restrict__ d4 = (f4*)deq_out;

    const int base = blockIdx.x * 1024 + tid;   // 4 float4/thread, stride 256

    if (base + 3 * 256 < n4) {
        // ---- fast path: all 4 tiles in range (every block for n4 % 1024 == 0)
        f4 xv[4], mv[4];
#pragma unroll
        for (int i = 0; i < 4; ++i) {
            xv[i] = __builtin_nontemporal_load(x4 + base + i * 256);
            mv[i] = __builtin_nontemporal_load(m4 + base + i * 256);
        }

        int idx[4][4];
#pragma unroll
        for (int i = 0; i < 4; ++i) {
            idx[i][0] = find_idx(xv[i].x - mv[i].x, ms, c0, invd);
            idx[i][1] = find_idx(xv[i].y - mv[i].y, ms, c0, invd);
            idx[i][2] = find_idx(xv[i].z - mv[i].z, ms, c0, invd);
            idx[i][3] = find_idx(xv[i].w - mv[i].w, ms, c0, invd);
        }

#pragma unroll
        for (int i = 0; i < 4; ++i) {
            f4 sv;
            sv.x = (float)idx[i][0];
            sv.y = (float)idx[i][1];
            sv.z = (float)idx[i][2];
            sv.w = (float)idx[i][3];
            f4 dv;
            dv.x = cb_s[idx[i][0]] + mv[i].x;
            dv.y = cb_s[idx[i][1]] + mv[i].y;
            dv.z = cb_s[idx[i][2]] + mv[i].z;
            dv.w = cb_s[idx[i][3]] + mv[i].w;
            __builtin_nontemporal_store(sv, s4 + base + i * 256);
            __builtin_nontemporal_store(dv, d4 + base + i * 256);
        }
    } else {
        // ---- tail path (not taken at this problem size; kept for safety)
        for (int i = 0; i < 4; ++i) {
            const int g = base + i * 256;
            if (g >= n4) break;
            const f4 xv = x4[g];
            const f4 mv = m4[g];
            const int i0 = find_idx(xv.x - mv.x, ms, c0, invd);
            const int i1 = find_idx(xv.y - mv.y, ms, c0, invd);
            const int i2 = find_idx(xv.z - mv.z, ms, c0, invd);
            const int i3 = find_idx(xv.w - mv.w, ms, c0, invd);
            f4 sv;
            sv.x = (float)i0; sv.y = (float)i1; sv.z = (float)i2; sv.w = (float)i3;
            f4 dv;
            dv.x = cb_s[i0] + mv.x;
            dv.y = cb_s[i1] + mv.y;
            dv.z = cb_s[i2] + mv.z;
            dv.w = cb_s[i3] + mv.w;
            s4[g] = sv;
            d4[g] = dv;
        }
    }
}

}  // namespace

extern "C" void kernel_launch(void* const* d_in, const int* in_sizes, int n_in,
                              void* d_out, int out_size, void* d_ws, size_t ws_size,
                              hipStream_t stream) {
    const float* x    = (const float*)d_in[0];
    const float* mean = (const float*)d_in[1];
    const float* cb   = (const float*)d_in[2];

    const int n = in_sizes[0];          // 28,311,552 (divisible by 1024*4)
    float* sym_out = (float*)d_out;     // outputs concatenated: [symbols | dequant]
    float* deq_out = sym_out + n;

    const int n4 = n / 4;               // 7,077,888 float4s
    const int block = 256;
    const int per_block = block * 4;    // 1024 float4s per block
    const int grid = (n4 + per_block - 1) / per_block;   // 6912, exact cover

    hipLaunchKernelGGL(stanh_quant_kernel, dim3(grid), dim3(block), 0, stream,
                       x, mean, cb, sym_out, deq_out, n4);
}